// Round 6
// baseline (337.553 us; speedup 1.0000x reference)
//
#include <hip/hip_runtime.h>
#include <hip/hip_bf16.h>
#include <math.h>

#define BB 8
#define NN 2048
#define HH 128
#define BN (BB*NN)   // 16384

typedef unsigned short ushort_t;
typedef __attribute__((ext_vector_type(8))) short short8_t;
typedef __attribute__((ext_vector_type(4))) float f32x4_t;

// ---------------------------------------------------------------------------
// workspace layout (bytes).  All B-operand matrices stored FRAGMENT-LINEAR:
// for each (kstep=k/32, colgroup=c/16): 64 lanes x 8 bf16 contiguous, so a
// wave's MFMA B-frag load is one 1KB contiguous read (no 16-line scatter).
// ---------------------------------------------------------------------------
#define WS_FLAG   0
#define WS_W1H    4096
#define WS_W1L    (WS_W1H + 32768)      // 128*128*2
#define WS_W2H    (WS_W1L + 32768)
#define WS_W2L    (WS_W2H + 32768)
#define WS_WIHH   (WS_W2L + 32768)      // 384*128*2 = 98304
#define WS_WIHL   (WS_WIHH + 98304)
#define WS_WHHH   (WS_WIHL + 98304)
#define WS_WHHL   (WS_WHHH + 98304)
#define WS_B1     (WS_WHHL + 98304)     // 528384
#define WS_B2     (WS_B1 + 512)
#define WS_BIH    (WS_B2 + 512)
#define WS_BHH    (WS_BIH + 1536)       // ends at 532480
#define WS_M      532480                // mT packed hi: [8][64 ks][8 cg][64][8] = 4 MiB
#define WS_MLO    (WS_M + 4194304)      // mT packed lo = 4 MiB (fp32 split path)

template<bool BF16>
__device__ __forceinline__ float ldf(const void* p, size_t off) {
    if constexpr (BF16) return (float)((const __bf16*)p)[off];
    else                return ((const float*)p)[off];
}

__device__ __forceinline__ float f4c(const float4 v, int i) {
    switch (i) { case 0: return v.x; case 1: return v.y; case 2: return v.z; default: return v.w; }
}

__device__ __forceinline__ ushort_t bf_rn(float v) {
    __bf16 b = (__bf16)v;
    return *(ushort_t*)&b;
}
__device__ __forceinline__ float bf_to_f(ushort_t u) {
    return __uint_as_float((unsigned)u << 16);
}
__device__ __forceinline__ float bfs_to_f(short s) {
    return __uint_as_float(((unsigned)(ushort_t)s) << 16);
}
__device__ __forceinline__ void split2(float v, ushort_t& hi, ushort_t& lo) {
    hi = bf_rn(v);
    lo = bf_rn(v - bf_to_f(hi));
}

__device__ __forceinline__ f32x4_t mfma16(short8_t a, short8_t b, f32x4_t c) {
    return __builtin_amdgcn_mfma_f32_16x16x32_bf16(a, b, c, 0, 0, 0);
}

// raw barrier without the __syncthreads vmcnt(0) drain: LDS-drain only.
__device__ __forceinline__ void lds_barrier() {
    asm volatile("s_waitcnt lgkmcnt(0)" ::: "memory");
    __builtin_amdgcn_s_barrier();
    __builtin_amdgcn_sched_barrier(0);
}

// ---------------------------------------------------------------------------
// prep: detect dtype from A's first 4096 ushorts (bf16 U(0,1): all <=0x3F80;
// fp32: ~37% exceed), publish flag, then split weights into bf16 hi/lo packed
// fragment-linear + widen biases to fp32.
// ---------------------------------------------------------------------------
template<bool BF16>
__device__ void prep_body(
    const void* W1, const void* b1, const void* W2, const void* b2,
    const void* Wih, const void* Whh, const void* bih, const void* bhh,
    char* ws)
{
    ushort_t* w1h = (ushort_t*)(ws + WS_W1H);
    ushort_t* w1l = (ushort_t*)(ws + WS_W1L);
    ushort_t* w2h = (ushort_t*)(ws + WS_W2H);
    ushort_t* w2l = (ushort_t*)(ws + WS_W2L);
    ushort_t* wihh = (ushort_t*)(ws + WS_WIHH);
    ushort_t* wihl = (ushort_t*)(ws + WS_WIHL);
    ushort_t* whhh = (ushort_t*)(ws + WS_WHHH);
    ushort_t* whhl = (ushort_t*)(ws + WS_WHHL);
    float* b1f  = (float*)(ws + WS_B1);
    float* b2f  = (float*)(ws + WS_B2);
    float* bihf = (float*)(ws + WS_BIH);
    float* bhhf = (float*)(ws + WS_BHH);

    int t = blockIdx.x * 256 + threadIdx.x;
    int nth = gridDim.x * 256;
    for (int i = t; i < HH * HH; i += nth) {
        int c = i >> 7, k = i & 127;
        int po = (((k >> 5) * 8 + (c >> 4)) * 64 + (c & 15) + 16 * ((k >> 3) & 3)) * 8 + (k & 7);
        ushort_t hi, lo;
        split2(ldf<BF16>(W1, i), hi, lo); w1h[po] = hi; w1l[po] = lo;
        split2(ldf<BF16>(W2, i), hi, lo); w2h[po] = hi; w2l[po] = lo;
    }
    for (int i = t; i < 3 * HH * HH; i += nth) {
        int c = i >> 7, k = i & 127;
        int po = (((k >> 5) * 24 + (c >> 4)) * 64 + (c & 15) + 16 * ((k >> 3) & 3)) * 8 + (k & 7);
        ushort_t hi, lo;
        split2(ldf<BF16>(Wih, i), hi, lo); wihh[po] = hi; wihl[po] = lo;
        split2(ldf<BF16>(Whh, i), hi, lo); whhh[po] = hi; whhl[po] = lo;
    }
    if (t < HH)     { b1f[t] = ldf<BF16>(b1, t);  b2f[t] = ldf<BF16>(b2, t); }
    if (t < 3 * HH) { bihf[t] = ldf<BF16>(bih, t); bhhf[t] = ldf<BF16>(bhh, t); }
}

__global__ __launch_bounds__(256) void prep_kernel(
    const ushort_t* __restrict__ Au,
    const void* W1, const void* b1, const void* W2, const void* b2,
    const void* Wih, const void* Whh, const void* bih, const void* bhh,
    char* __restrict__ ws, int* __restrict__ flag)
{
    __shared__ int cnt;
    if (threadIdx.x == 0) cnt = 0;
    __syncthreads();
    int c = 0;
    for (int i = threadIdx.x; i < 4096; i += 256)
        if (Au[i] > 0x3F80u) ++c;
    atomicAdd(&cnt, c);
    __syncthreads();
    const bool isbf = (cnt < 100);
    if (blockIdx.x == 0 && threadIdx.x == 0) *flag = isbf ? 1 : 0;
    if (isbf) prep_body<true >(W1, b1, W2, b2, Wih, Whh, bih, bhh, ws);
    else      prep_body<false>(W1, b1, W2, b2, Wih, Whh, bih, bhh, ws);
}

// ---------------------------------------------------------------------------
// MLP via MFMA; weights from packed frag-linear; exports mT packed
// frag-linear (hi + lo when SPLIT) for the msg kernel.  (unchanged from R5)
// ---------------------------------------------------------------------------
template<bool BF16, bool SPLIT>
__device__ void mlp_body(char* smem, const void* h, char* ws)
{
    float    (*hf)[132]  = (float(*)[132])smem;             // 16896 B
    ushort_t (*m1h)[264] = (ushort_t(*)[264])(smem + 16896);
    ushort_t (*m1l)[264] = (ushort_t(*)[264])(smem + 33792);

    const ushort_t* w1h = (const ushort_t*)(ws + WS_W1H);
    const ushort_t* w1l = (const ushort_t*)(ws + WS_W1L);
    const ushort_t* w2h = (const ushort_t*)(ws + WS_W2H);
    const ushort_t* w2l = (const ushort_t*)(ws + WS_W2L);
    const float* b1f = (const float*)(ws + WS_B1);
    const float* b2f = (const float*)(ws + WS_B2);
    ushort_t* mTh = (ushort_t*)(ws + WS_M);
    ushort_t* mTl = (ushort_t*)(ws + WS_MLO);

    const int tid = threadIdx.x;
    const int row0 = blockIdx.x * 32;

    if constexpr (BF16) {
#pragma unroll
        for (int j = 0; j < 2; ++j) {
            int e = j * 256 + tid;
            int r = e >> 4, c8 = (e & 15) * 8;
            short8_t v = *reinterpret_cast<const short8_t*>((const ushort_t*)h + (size_t)(row0 + r) * HH + c8);
#pragma unroll
            for (int q = 0; q < 8; ++q) hf[r][c8 + q] = bfs_to_f(v[q]);
        }
    } else {
#pragma unroll
        for (int j = 0; j < 4; ++j) {
            int e = j * 256 + tid;
            int r = e >> 5, c4 = (e & 31) * 4;
            *(float4*)&hf[r][c4] = *reinterpret_cast<const float4*>((const float*)h + (size_t)(row0 + r) * HH + c4);
        }
    }
    __syncthreads();

    const int lane = tid & 63, wv = tid >> 6;
    const int lr = lane & 15, hq = lane >> 4;
    const int rt = wv & 1, ct0 = (wv >> 1) * 4;

    // ---- layer 1 ----
    f32x4_t acc[4];
#pragma unroll
    for (int c = 0; c < 4; ++c) { acc[c][0] = 0.f; acc[c][1] = 0.f; acc[c][2] = 0.f; acc[c][3] = 0.f; }

    for (int k0 = 0; k0 < HH; k0 += 32) {
        short8_t ahh, ahl;
        {
            float4 f0 = *(const float4*)&hf[rt * 16 + lr][k0 + 8 * hq];
            float4 f1 = *(const float4*)&hf[rt * 16 + lr][k0 + 8 * hq + 4];
#pragma unroll
            for (int j = 0; j < 4; ++j) {
                ushort_t hi, lo;
                split2(f4c(f0, j), hi, lo); ahh[j] = (short)hi; ahl[j] = (short)lo;
                split2(f4c(f1, j), hi, lo); ahh[j + 4] = (short)hi; ahl[j + 4] = (short)lo;
            }
        }
        const int ks = k0 >> 5;
#pragma unroll
        for (int c = 0; c < 4; ++c) {
            size_t po = ((size_t)(ks * 8 + ct0 + c)) * 512 + (size_t)lane * 8;
            short8_t bh = *reinterpret_cast<const short8_t*>(w1h + po);
            acc[c] = mfma16(ahh, bh, acc[c]);
            if constexpr (!BF16) {
                short8_t bl = *reinterpret_cast<const short8_t*>(w1l + po);
                acc[c] = mfma16(ahl, bh, acc[c]);
                acc[c] = mfma16(ahh, bl, acc[c]);
            }
        }
    }
#pragma unroll
    for (int c = 0; c < 4; ++c) {
        int col = (ct0 + c) * 16 + lr;
        float bv = b1f[col];
#pragma unroll
        for (int q = 0; q < 4; ++q) {
            int row = rt * 16 + hq * 4 + q;
            float v = fmaxf(acc[c][q] + bv, 0.f);
            ushort_t hi, lo;
            split2(v, hi, lo);
            m1h[row][col] = hi;
            if constexpr (!BF16) m1l[row][col] = lo;
        }
    }
    __syncthreads();

    // ---- layer 2 ----
    f32x4_t acc2[4];
#pragma unroll
    for (int c = 0; c < 4; ++c) { acc2[c][0] = 0.f; acc2[c][1] = 0.f; acc2[c][2] = 0.f; acc2[c][3] = 0.f; }

    for (int k0 = 0; k0 < HH; k0 += 32) {
        short8_t amh = *reinterpret_cast<const short8_t*>(&m1h[rt * 16 + lr][k0 + 8 * hq]);
        short8_t aml;
        if constexpr (!BF16) aml = *reinterpret_cast<const short8_t*>(&m1l[rt * 16 + lr][k0 + 8 * hq]);
        const int ks = k0 >> 5;
#pragma unroll
        for (int c = 0; c < 4; ++c) {
            size_t po = ((size_t)(ks * 8 + ct0 + c)) * 512 + (size_t)lane * 8;
            short8_t bh = *reinterpret_cast<const short8_t*>(w2h + po);
            acc2[c] = mfma16(amh, bh, acc2[c]);
            if constexpr (!BF16) {
                short8_t bl = *reinterpret_cast<const short8_t*>(w2l + po);
                acc2[c] = mfma16(aml, bh, acc2[c]);
                acc2[c] = mfma16(amh, bl, acc2[c]);
            }
        }
    }
    {
        const int bb = row0 >> 11, nb = row0 & 2047;
#pragma unroll
        for (int c = 0; c < 4; ++c) {
            int col = (ct0 + c) * 16 + lr;
            float bv = b2f[col];
#pragma unroll
            for (int q = 0; q < 4; ++q) {
                int nn = nb + rt * 16 + hq * 4 + q;
                float v = fmaxf(acc2[c][q] + bv, 0.f);
                ushort_t hi, lo;
                split2(v, hi, lo);
                size_t po = (((size_t)(bb * 64 + (nn >> 5)) * 8 + (ct0 + c)) * 64
                             + lr + 16 * ((nn >> 3) & 3)) * 8 + (nn & 7);
                mTh[po] = hi;
                if constexpr (SPLIT) mTl[po] = lo;
            }
        }
    }
}

template<bool SPLIT>
__global__ __launch_bounds__(256) void mlp_kernel(
    const int* __restrict__ flag, const void* __restrict__ h, char* __restrict__ ws)
{
    __shared__ __align__(16) char smem[50688];
    if (*flag) mlp_body<true, false>(smem, h, ws);
    else       mlp_body<false, SPLIT>(smem, h, ws);
}

// ---------------------------------------------------------------------------
// msg = relu(A@m) via MFMA.  Deep-pipelined: 4-deep register ring for A,
// double-buffered LDS tiles, ONE raw barrier per k-tile (lgkmcnt drain only
// -- NO vmcnt(0), so A prefetch loads stay in flight across barriers).
// A loads issued AFTER the tile's B-loads => the MFMA B-wait leaves them
// outstanding (vmcnt FIFO).  Epilogue stores via LDS transpose (contiguous
// 16B stores, no 2B-scatter RMW amplification).
// ---------------------------------------------------------------------------
template<bool BF16, bool SPLIT>
__device__ void msg_body(char* smem, const void* A, const char* ws, void* out)
{
    ushort_t (*Ah)[32][72] = (ushort_t(*)[32][72])smem;            // 2*4608 = 9216
    ushort_t (*Al)[32][72] = (ushort_t(*)[32][72])(smem + 9216);   // fp32 only
    const ushort_t* mThp = (const ushort_t*)(ws + WS_M);
    const ushort_t* mTlp = (const ushort_t*)(ws + WS_MLO);

    const int tid = threadIdx.x;
    const int b = blockIdx.x & 7, rtile = blockIdx.x >> 3;
    const int n0 = rtile * 32;
    const int lane = tid & 63, wv = tid >> 6;
    const int lr = lane & 15, hq = lane >> 4;
    const int wr = (wv & 1) * 16, wc4 = (wv >> 1) * 4;

    f32x4_t acc[4];
#pragma unroll
    for (int t = 0; t < 4; ++t) { acc[t][0] = 0.f; acc[t][1] = 0.f; acc[t][2] = 0.f; acc[t][3] = 0.f; }

    const int er0 = tid >> 4, ec0 = (tid & 15) * 4;   // fp32 staging map
    const int br_ = tid >> 3, bc_ = (tid & 7) * 8;    // bf16 staging map

    short8_t rB[4];
    float4   rF0[4], rF1[4];

    auto issue = [&](int t) {
        int slot = t & 3;
        if constexpr (BF16) {
            rB[slot] = *reinterpret_cast<const short8_t*>(
                (const ushort_t*)A + ((size_t)(b * NN + n0 + br_)) * NN + t * 64 + bc_);
        } else {
            const float* ap = (const float*)A;
            rF0[slot] = *reinterpret_cast<const float4*>(ap + ((size_t)(b * NN + n0 + er0)) * NN + t * 64 + ec0);
            rF1[slot] = *reinterpret_cast<const float4*>(ap + ((size_t)(b * NN + n0 + er0 + 16)) * NN + t * 64 + ec0);
        }
    };
    auto stage = [&](int t) {
        int slot = t & 3, buf = t & 1;
        if constexpr (BF16) {
            *reinterpret_cast<short8_t*>(&Ah[buf][br_][bc_]) = rB[slot];
        } else {
            ushort4 h4, l4;
            float4 v = rF0[slot];
            split2(v.x, h4.x, l4.x); split2(v.y, h4.y, l4.y);
            split2(v.z, h4.z, l4.z); split2(v.w, h4.w, l4.w);
            *reinterpret_cast<ushort4*>(&Ah[buf][er0][ec0]) = h4;
            *reinterpret_cast<ushort4*>(&Al[buf][er0][ec0]) = l4;
            v = rF1[slot];
            split2(v.x, h4.x, l4.x); split2(v.y, h4.y, l4.y);
            split2(v.z, h4.z, l4.z); split2(v.w, h4.w, l4.w);
            *reinterpret_cast<ushort4*>(&Ah[buf][er0 + 16][ec0]) = h4;
            *reinterpret_cast<ushort4*>(&Al[buf][er0 + 16][ec0]) = l4;
        }
    };

    // prologue: tiles 0..3 issued; tile0 staged into buf0
    issue(0); issue(1);
    stage(0);
    issue(2); issue(3);
    lds_barrier();

    for (int kt = 0; kt < 32; ++kt) {
        if (kt + 1 < 32) stage(kt + 1);       // buf[(kt+1)&1]; readers finished last iter
        const int cur = kt & 1;
#pragma unroll
        for (int kh = 0; kh < 2; ++kh) {
            short8_t ah = *reinterpret_cast<const short8_t*>(&Ah[cur][wr + lr][kh * 32 + 8 * hq]);
            short8_t al;
            if constexpr (!BF16) al = *reinterpret_cast<const short8_t*>(&Al[cur][wr + lr][kh * 32 + 8 * hq]);
            const size_t pb = ((size_t)(b * 64 + kt * 2 + kh) * 8 + wc4) * 512 + (size_t)lane * 8;
            short8_t bh[4], bl[4];
#pragma unroll
            for (int t = 0; t < 4; ++t)
                bh[t] = *reinterpret_cast<const short8_t*>(mThp + pb + t * 512);
            if constexpr (!BF16 && SPLIT) {
#pragma unroll
                for (int t = 0; t < 4; ++t)
                    bl[t] = *reinterpret_cast<const short8_t*>(mTlp + pb + t * 512);
            }
            if (kh == 0 && kt + 4 < 32) issue(kt + 4);   // after B-loads: stays in flight
#pragma unroll
            for (int t = 0; t < 4; ++t) {
                acc[t] = mfma16(ah, bh[t], acc[t]);
                if constexpr (!BF16) {
                    acc[t] = mfma16(al, bh[t], acc[t]);
                    if constexpr (SPLIT) acc[t] = mfma16(ah, bl[t], acc[t]);
                }
            }
        }
        lds_barrier();
    }

    // ---- epilogue: stage results in LDS, store contiguous 16B chunks ----
    ushort_t (*Sh)[136] = (ushort_t(*)[136])smem;            // 8704 B
    ushort_t (*Sl)[136] = (ushort_t(*)[136])(smem + 8704);   // 8704 B (fp32)
    const int wc = wc4 * 16;
#pragma unroll
    for (int t = 0; t < 4; ++t)
#pragma unroll
        for (int q = 0; q < 4; ++q) {
            int row = wr + hq * 4 + q, col = wc + t * 16 + lr;
            float v = fmaxf(acc[t][q], 0.f);
            if constexpr (BF16) {
                Sh[row][col] = bf_rn(v);
            } else {
                ushort_t hi, lo;
                split2(v, hi, lo);
                Sh[row][col] = hi;
                Sl[row][col] = lo;
            }
        }
    __syncthreads();

    char* ob = (char*)out;
    if constexpr (BF16) {
#pragma unroll
        for (int j = 0; j < 2; ++j) {
            int c = j * 256 + tid;
            int row = c >> 4, o16 = c & 15;
            short8_t v = *reinterpret_cast<const short8_t*>(&Sh[row][o16 * 8]);
            *reinterpret_cast<short8_t*>(ob + (size_t)(b * NN + n0 + row) * 256 + o16 * 16) = v;
        }
    } else {
#pragma unroll
        for (int j = 0; j < 4; ++j) {
            int c = j * 256 + tid;
            int row = c >> 5, rem = c & 31;
            int half = rem >> 4, o16 = rem & 15;
            const ushort_t* src = half ? &Sl[row][o16 * 8] : &Sh[row][o16 * 8];
            short8_t v = *reinterpret_cast<const short8_t*>(src);
            *reinterpret_cast<short8_t*>(ob + (size_t)(b * NN + n0 + row) * 512 + half * 256 + o16 * 16) = v;
        }
    }
}

template<bool SPLIT>
__global__ __launch_bounds__(256) void msg_kernel(
    const int* __restrict__ flag, const void* __restrict__ A,
    const char* __restrict__ ws, void* __restrict__ out)
{
    __shared__ __align__(16) char smem[18432];
    if (*flag) msg_body<true, false>(smem, A, (const char*)ws, out);
    else       msg_body<false, SPLIT>(smem, A, (const char*)ws, out);
}

// ---------------------------------------------------------------------------
// GRU via MFMA, weights from packed frag-linear.  (unchanged from R5)
// ---------------------------------------------------------------------------
template<bool BF16>
__device__ void gru_body(char* smem, const void* h, const char* ws, void* out)
{
    ushort_t (*msgh)[264] = (ushort_t(*)[264])smem;               // 16896
    ushort_t (*msgl)[264] = (ushort_t(*)[264])(smem + 16896);
    float    (*hf)[132]   = (float(*)[132])(smem + 33792);

    const ushort_t* wihh = (const ushort_t*)(ws + WS_WIHH);
    const ushort_t* wihl = (const ushort_t*)(ws + WS_WIHL);
    const ushort_t* whhh = (const ushort_t*)(ws + WS_WHHH);
    const ushort_t* whhl = (const ushort_t*)(ws + WS_WHHL);
    const float* bihf = (const float*)(ws + WS_BIH);
    const float* bhhf = (const float*)(ws + WS_BHH);

    const int tid = threadIdx.x;
    const int row0 = blockIdx.x * 32;
    char* ob = (char*)out;

    if constexpr (BF16) {
#pragma unroll
        for (int j = 0; j < 2; ++j) {
            int e = j * 256 + tid;
            int r = e >> 4, c8 = (e & 15) * 8;
            short8_t v = *reinterpret_cast<const short8_t*>(ob + (size_t)(row0 + r) * 256 + c8 * 2);
            *(short8_t*)&msgh[r][c8] = v;
        }
    } else {
#pragma unroll
        for (int j = 0; j < 4; ++j) {
            int e = j * 256 + tid;
            int r = e >> 5, off = (e & 31) * 16;
            short8_t v = *reinterpret_cast<const short8_t*>(ob + (size_t)(row0 + r) * 512 + off);
            if (off < 256) *(short8_t*)&msgh[r][off >> 1] = v;
            else           *(short8_t*)&msgl[r][(off - 256) >> 1] = v;
        }
    }
    if constexpr (BF16) {
#pragma unroll
        for (int j = 0; j < 2; ++j) {
            int e = j * 256 + tid;
            int r = e >> 4, c8 = (e & 15) * 8;
            short8_t v = *reinterpret_cast<const short8_t*>((const ushort_t*)h + (size_t)(row0 + r) * HH + c8);
#pragma unroll
            for (int q = 0; q < 8; ++q) hf[r][c8 + q] = bfs_to_f(v[q]);
        }
    } else {
#pragma unroll
        for (int j = 0; j < 4; ++j) {
            int e = j * 256 + tid;
            int r = e >> 5, c4 = (e & 31) * 4;
            *(float4*)&hf[r][c4] = *reinterpret_cast<const float4*>((const float*)h + (size_t)(row0 + r) * HH + c4);
        }
    }
    __syncthreads();

    const int lane = tid & 63, wv = tid >> 6;
    const int lr = lane & 15, hq = lane >> 4;
    const int cw0 = wv * 32;

    f32x4_t accx[2][3][2], acch[2][3][2];
#pragma unroll
    for (int rt = 0; rt < 2; ++rt)
#pragma unroll
        for (int g = 0; g < 3; ++g)
#pragma unroll
            for (int ct = 0; ct < 2; ++ct) {
                accx[rt][g][ct][0] = 0.f; accx[rt][g][ct][1] = 0.f;
                accx[rt][g][ct][2] = 0.f; accx[rt][g][ct][3] = 0.f;
                acch[rt][g][ct][0] = 0.f; acch[rt][g][ct][1] = 0.f;
                acch[rt][g][ct][2] = 0.f; acch[rt][g][ct][3] = 0.f;
            }

    for (int k0 = 0; k0 < HH; k0 += 32) {
        short8_t amh[2], aml[2], ahh[2], ahl[2];
#pragma unroll
        for (int rt = 0; rt < 2; ++rt) {
            amh[rt] = *reinterpret_cast<const short8_t*>(&msgh[rt * 16 + lr][k0 + 8 * hq]);
            if constexpr (!BF16)
                aml[rt] = *reinterpret_cast<const short8_t*>(&msgl[rt * 16 + lr][k0 + 8 * hq]);
            float4 f0 = *(const float4*)&hf[rt * 16 + lr][k0 + 8 * hq];
            float4 f1 = *(const float4*)&hf[rt * 16 + lr][k0 + 8 * hq + 4];
#pragma unroll
            for (int j = 0; j < 4; ++j) {
                ushort_t hi, lo;
                split2(f4c(f0, j), hi, lo); ahh[rt][j] = (short)hi; ahl[rt][j] = (short)lo;
                split2(f4c(f1, j), hi, lo); ahh[rt][j + 4] = (short)hi; ahl[rt][j + 4] = (short)lo;
            }
        }
        const int ks = k0 >> 5;
#pragma unroll
        for (int g = 0; g < 3; ++g)
#pragma unroll
            for (int ct = 0; ct < 2; ++ct) {
                const size_t po = ((size_t)(ks * 24 + g * 8 + wv * 2 + ct)) * 512 + (size_t)lane * 8;
                short8_t bxh  = *reinterpret_cast<const short8_t*>(wihh + po);
                short8_t bhh2 = *reinterpret_cast<const short8_t*>(whhh + po);
                short8_t bxl, bhl2;
                if constexpr (!BF16) {
                    bxl  = *reinterpret_cast<const short8_t*>(wihl + po);
                    bhl2 = *reinterpret_cast<const short8_t*>(whhl + po);
                }
#pragma unroll
                for (int rt = 0; rt < 2; ++rt) {
                    accx[rt][g][ct] = mfma16(amh[rt], bxh, accx[rt][g][ct]);
                    acch[rt][g][ct] = mfma16(ahh[rt], bhh2, acch[rt][g][ct]);
                    if constexpr (!BF16) {
                        accx[rt][g][ct] = mfma16(aml[rt], bxh, accx[rt][g][ct]);
                        accx[rt][g][ct] = mfma16(amh[rt], bxl, accx[rt][g][ct]);
                        acch[rt][g][ct] = mfma16(ahl[rt], bhh2, acch[rt][g][ct]);
                        acch[rt][g][ct] = mfma16(ahh[rt], bhl2, acch[rt][g][ct]);
                    }
                }
            }
    }

#pragma unroll
    for (int rt = 0; rt < 2; ++rt)
#pragma unroll
        for (int ct = 0; ct < 2; ++ct) {
            int col = cw0 + ct * 16 + lr;
            float brx = bihf[col],       brh = bhhf[col];
            float bzx = bihf[128 + col], bzh = bhhf[128 + col];
            float bnx = bihf[256 + col], bnh = bhhf[256 + col];
#pragma unroll
            for (int q = 0; q < 4; ++q) {
                int row = rt * 16 + hq * 4 + q;
                float gr_ = (accx[rt][0][ct][q] + brx) + (acch[rt][0][ct][q] + brh);
                float gz_ = (accx[rt][1][ct][q] + bzx) + (acch[rt][1][ct][q] + bzh);
                float gxn = accx[rt][2][ct][q] + bnx;
                float ghn = acch[rt][2][ct][q] + bnh;
                float rr = 1.f / (1.f + expf(-gr_));
                float zz = 1.f / (1.f + expf(-gz_));
                float nv = tanhf(gxn + rr * ghn);
                float hv = hf[row][col];
                float res = (1.f - zz) * nv + zz * hv;
                size_t o = (size_t)(row0 + row) * HH + col;
                if constexpr (BF16) ((ushort_t*)out)[o] = bf_rn(res);
                else                ((float*)out)[o]    = res;
            }
        }
}

__global__ __launch_bounds__(256) __attribute__((amdgpu_waves_per_eu(1, 2)))
void gru_kernel(
    const int* __restrict__ flag, const void* __restrict__ h,
    const char* __restrict__ ws, void* __restrict__ out)
{
    __shared__ __align__(16) char smem[50688];
    if (*flag) gru_body<true >(smem, h, (const char*)ws, out);
    else       gru_body<false>(smem, h, (const char*)ws, out);
}

// ---------------------------------------------------------------------------
// diagnostic fill
// ---------------------------------------------------------------------------
__global__ void diag_kernel(float* __restrict__ out, float val, int nfill)
{
    int i = blockIdx.x * 256 + threadIdx.x;
    if (i < nfill) out[i] = val;
}

// ---------------------------------------------------------------------------
extern "C" void kernel_launch(void* const* d_in, const int* in_sizes, int n_in,
                              void* d_out, int out_size, void* d_ws, size_t ws_size,
                              hipStream_t stream)
{
    const int expected[10] = {BN * HH, BB * NN * NN, HH * HH, HH, HH * HH, HH,
                              3 * HH * HH, 3 * HH * HH, 3 * HH, 3 * HH};
    int bad = -1;
    if (n_in < 10) bad = 50;
    else {
        for (int i = 0; i < 10; ++i)
            if (in_sizes[i] != expected[i]) { bad = i; break; }
    }
    if (bad < 0 && out_size != BN * HH) bad = 60;
    if (bad >= 0) {
        float val = 10000.0f + 1000.0f * (float)bad;
        int nfill = out_size / 2;
        diag_kernel<<<(nfill + 255) / 256, 256, 0, stream>>>((float*)d_out, val, nfill);
        return;
    }

    const void* h   = d_in[0];
    const void* A   = d_in[1];
    const void* W1  = d_in[2];
    const void* b1  = d_in[3];
    const void* W2  = d_in[4];
    const void* b2  = d_in[5];
    const void* Wih = d_in[6];
    const void* Whh = d_in[7];
    const void* bih = d_in[8];
    const void* bhh = d_in[9];

    const size_t need_bf  = WS_M + (size_t)BN * HH * 2;    // packed mT hi only
    const size_t need_f32 = WS_M + (size_t)BN * HH * 4;    // + packed mT lo
    if (ws_size < need_bf) {
        float val = 2000.0f + (float)(ws_size >> 10);
        int nfill = out_size / 2;
        diag_kernel<<<(nfill + 255) / 256, 256, 0, stream>>>((float*)d_out, val, nfill);
        return;
    }
    const bool split = (ws_size >= need_f32);
    int*  flag = (int*)d_ws;
    char* ws   = (char*)d_ws;

    prep_kernel<<<64, 256, 0, stream>>>((const ushort_t*)A, W1, b1, W2, b2,
                                        Wih, Whh, bih, bhh, ws, flag);

    if (split) {
        mlp_kernel<true ><<<BN / 32, 256, 0, stream>>>(flag, h, ws);
        msg_kernel<true ><<<BB * (NN / 32), 256, 0, stream>>>(flag, A, ws, d_out);
    } else {
        mlp_kernel<false><<<BN / 32, 256, 0, stream>>>(flag, h, ws);
        msg_kernel<false><<<BB * (NN / 32), 256, 0, stream>>>(flag, A, ws, d_out);
    }
    gru_kernel<<<BN / 32, 256, 0, stream>>>(flag, h, ws, d_out);
}

// Round 7
// 290.224 us; speedup vs baseline: 1.1631x; 1.1631x over previous
//
#include <hip/hip_runtime.h>
#include <hip/hip_bf16.h>
#include <math.h>

#define BB 8
#define NN 2048
#define HH 128
#define BN (BB*NN)   // 16384

typedef unsigned short ushort_t;
typedef __attribute__((ext_vector_type(8))) short short8_t;
typedef __attribute__((ext_vector_type(4))) float f32x4_t;

// ---------------------------------------------------------------------------
// workspace layout (bytes).  All B-operand matrices stored FRAGMENT-LINEAR:
// for each (kstep=k/32, colgroup=c/16): 64 lanes x 8 bf16 contiguous, so a
// wave's MFMA B-frag load is one 1KB contiguous read (no 16-line scatter).
// ---------------------------------------------------------------------------
#define WS_FLAG   0
#define WS_W1H    4096
#define WS_W1L    (WS_W1H + 32768)      // 128*128*2
#define WS_W2H    (WS_W1L + 32768)
#define WS_W2L    (WS_W2H + 32768)
#define WS_WIHH   (WS_W2L + 32768)      // 384*128*2 = 98304
#define WS_WIHL   (WS_WIHH + 98304)
#define WS_WHHH   (WS_WIHL + 98304)
#define WS_WHHL   (WS_WHHH + 98304)
#define WS_B1     (WS_WHHL + 98304)     // 528384
#define WS_B2     (WS_B1 + 512)
#define WS_BIH    (WS_B2 + 512)
#define WS_BHH    (WS_BIH + 1536)       // ends at 532480
#define WS_M      532480                // mT packed hi: [8][64 ks][8 cg][64][8] = 4 MiB
#define WS_MLO    (WS_M + 4194304)      // mT packed lo = 4 MiB (fp32 split path)

template<bool BF16>
__device__ __forceinline__ float ldf(const void* p, size_t off) {
    if constexpr (BF16) return (float)((const __bf16*)p)[off];
    else                return ((const float*)p)[off];
}

__device__ __forceinline__ float f4c(const float4 v, int i) {
    switch (i) { case 0: return v.x; case 1: return v.y; case 2: return v.z; default: return v.w; }
}

__device__ __forceinline__ ushort_t bf_rn(float v) {
    __bf16 b = (__bf16)v;
    return *(ushort_t*)&b;
}
__device__ __forceinline__ float bf_to_f(ushort_t u) {
    return __uint_as_float((unsigned)u << 16);
}
__device__ __forceinline__ float bfs_to_f(short s) {
    return __uint_as_float(((unsigned)(ushort_t)s) << 16);
}
__device__ __forceinline__ void split2(float v, ushort_t& hi, ushort_t& lo) {
    hi = bf_rn(v);
    lo = bf_rn(v - bf_to_f(hi));
}

__device__ __forceinline__ f32x4_t mfma16(short8_t a, short8_t b, f32x4_t c) {
    return __builtin_amdgcn_mfma_f32_16x16x32_bf16(a, b, c, 0, 0, 0);
}

// raw barrier without the __syncthreads vmcnt(0) drain: LDS-drain only.
__device__ __forceinline__ void lds_barrier() {
    asm volatile("s_waitcnt lgkmcnt(0)" ::: "memory");
    __builtin_amdgcn_s_barrier();
    __builtin_amdgcn_sched_barrier(0);
}

// ---------------------------------------------------------------------------
// prep: detect dtype from A's first 4096 ushorts (bf16 U(0,1): all <=0x3F80;
// fp32: ~37% exceed), publish flag, then split weights into bf16 hi/lo packed
// fragment-linear + widen biases to fp32.
// ---------------------------------------------------------------------------
template<bool BF16>
__device__ void prep_body(
    const void* W1, const void* b1, const void* W2, const void* b2,
    const void* Wih, const void* Whh, const void* bih, const void* bhh,
    char* ws)
{
    ushort_t* w1h = (ushort_t*)(ws + WS_W1H);
    ushort_t* w1l = (ushort_t*)(ws + WS_W1L);
    ushort_t* w2h = (ushort_t*)(ws + WS_W2H);
    ushort_t* w2l = (ushort_t*)(ws + WS_W2L);
    ushort_t* wihh = (ushort_t*)(ws + WS_WIHH);
    ushort_t* wihl = (ushort_t*)(ws + WS_WIHL);
    ushort_t* whhh = (ushort_t*)(ws + WS_WHHH);
    ushort_t* whhl = (ushort_t*)(ws + WS_WHHL);
    float* b1f  = (float*)(ws + WS_B1);
    float* b2f  = (float*)(ws + WS_B2);
    float* bihf = (float*)(ws + WS_BIH);
    float* bhhf = (float*)(ws + WS_BHH);

    int t = blockIdx.x * 256 + threadIdx.x;
    int nth = gridDim.x * 256;
    for (int i = t; i < HH * HH; i += nth) {
        int c = i >> 7, k = i & 127;
        int po = (((k >> 5) * 8 + (c >> 4)) * 64 + (c & 15) + 16 * ((k >> 3) & 3)) * 8 + (k & 7);
        ushort_t hi, lo;
        split2(ldf<BF16>(W1, i), hi, lo); w1h[po] = hi; w1l[po] = lo;
        split2(ldf<BF16>(W2, i), hi, lo); w2h[po] = hi; w2l[po] = lo;
    }
    for (int i = t; i < 3 * HH * HH; i += nth) {
        int c = i >> 7, k = i & 127;
        int po = (((k >> 5) * 24 + (c >> 4)) * 64 + (c & 15) + 16 * ((k >> 3) & 3)) * 8 + (k & 7);
        ushort_t hi, lo;
        split2(ldf<BF16>(Wih, i), hi, lo); wihh[po] = hi; wihl[po] = lo;
        split2(ldf<BF16>(Whh, i), hi, lo); whhh[po] = hi; whhl[po] = lo;
    }
    if (t < HH)     { b1f[t] = ldf<BF16>(b1, t);  b2f[t] = ldf<BF16>(b2, t); }
    if (t < 3 * HH) { bihf[t] = ldf<BF16>(bih, t); bhhf[t] = ldf<BF16>(bhh, t); }
}

__global__ __launch_bounds__(256) void prep_kernel(
    const ushort_t* __restrict__ Au,
    const void* W1, const void* b1, const void* W2, const void* b2,
    const void* Wih, const void* Whh, const void* bih, const void* bhh,
    char* __restrict__ ws, int* __restrict__ flag)
{
    __shared__ int cnt;
    if (threadIdx.x == 0) cnt = 0;
    __syncthreads();
    int c = 0;
    for (int i = threadIdx.x; i < 4096; i += 256)
        if (Au[i] > 0x3F80u) ++c;
    atomicAdd(&cnt, c);
    __syncthreads();
    const bool isbf = (cnt < 100);
    if (blockIdx.x == 0 && threadIdx.x == 0) *flag = isbf ? 1 : 0;
    if (isbf) prep_body<true >(W1, b1, W2, b2, Wih, Whh, bih, bhh, ws);
    else      prep_body<false>(W1, b1, W2, b2, Wih, Whh, bih, bhh, ws);
}

// ---------------------------------------------------------------------------
// MLP via MFMA; weights from packed frag-linear; exports mT packed
// frag-linear (hi + lo when SPLIT) for the msg kernel.  (unchanged)
// ---------------------------------------------------------------------------
template<bool BF16, bool SPLIT>
__device__ void mlp_body(char* smem, const void* h, char* ws)
{
    float    (*hf)[132]  = (float(*)[132])smem;             // 16896 B
    ushort_t (*m1h)[264] = (ushort_t(*)[264])(smem + 16896);
    ushort_t (*m1l)[264] = (ushort_t(*)[264])(smem + 33792);

    const ushort_t* w1h = (const ushort_t*)(ws + WS_W1H);
    const ushort_t* w1l = (const ushort_t*)(ws + WS_W1L);
    const ushort_t* w2h = (const ushort_t*)(ws + WS_W2H);
    const ushort_t* w2l = (const ushort_t*)(ws + WS_W2L);
    const float* b1f = (const float*)(ws + WS_B1);
    const float* b2f = (const float*)(ws + WS_B2);
    ushort_t* mTh = (ushort_t*)(ws + WS_M);
    ushort_t* mTl = (ushort_t*)(ws + WS_MLO);

    const int tid = threadIdx.x;
    const int row0 = blockIdx.x * 32;

    if constexpr (BF16) {
#pragma unroll
        for (int j = 0; j < 2; ++j) {
            int e = j * 256 + tid;
            int r = e >> 4, c8 = (e & 15) * 8;
            short8_t v = *reinterpret_cast<const short8_t*>((const ushort_t*)h + (size_t)(row0 + r) * HH + c8);
#pragma unroll
            for (int q = 0; q < 8; ++q) hf[r][c8 + q] = bfs_to_f(v[q]);
        }
    } else {
#pragma unroll
        for (int j = 0; j < 4; ++j) {
            int e = j * 256 + tid;
            int r = e >> 5, c4 = (e & 31) * 4;
            *(float4*)&hf[r][c4] = *reinterpret_cast<const float4*>((const float*)h + (size_t)(row0 + r) * HH + c4);
        }
    }
    __syncthreads();

    const int lane = tid & 63, wv = tid >> 6;
    const int lr = lane & 15, hq = lane >> 4;
    const int rt = wv & 1, ct0 = (wv >> 1) * 4;

    // ---- layer 1 ----
    f32x4_t acc[4];
#pragma unroll
    for (int c = 0; c < 4; ++c) { acc[c][0] = 0.f; acc[c][1] = 0.f; acc[c][2] = 0.f; acc[c][3] = 0.f; }

    for (int k0 = 0; k0 < HH; k0 += 32) {
        short8_t ahh, ahl;
        {
            float4 f0 = *(const float4*)&hf[rt * 16 + lr][k0 + 8 * hq];
            float4 f1 = *(const float4*)&hf[rt * 16 + lr][k0 + 8 * hq + 4];
#pragma unroll
            for (int j = 0; j < 4; ++j) {
                ushort_t hi, lo;
                split2(f4c(f0, j), hi, lo); ahh[j] = (short)hi; ahl[j] = (short)lo;
                split2(f4c(f1, j), hi, lo); ahh[j + 4] = (short)hi; ahl[j + 4] = (short)lo;
            }
        }
        const int ks = k0 >> 5;
#pragma unroll
        for (int c = 0; c < 4; ++c) {
            size_t po = ((size_t)(ks * 8 + ct0 + c)) * 512 + (size_t)lane * 8;
            short8_t bh = *reinterpret_cast<const short8_t*>(w1h + po);
            acc[c] = mfma16(ahh, bh, acc[c]);
            if constexpr (!BF16) {
                short8_t bl = *reinterpret_cast<const short8_t*>(w1l + po);
                acc[c] = mfma16(ahl, bh, acc[c]);
                acc[c] = mfma16(ahh, bl, acc[c]);
            }
        }
    }
#pragma unroll
    for (int c = 0; c < 4; ++c) {
        int col = (ct0 + c) * 16 + lr;
        float bv = b1f[col];
#pragma unroll
        for (int q = 0; q < 4; ++q) {
            int row = rt * 16 + hq * 4 + q;
            float v = fmaxf(acc[c][q] + bv, 0.f);
            ushort_t hi, lo;
            split2(v, hi, lo);
            m1h[row][col] = hi;
            if constexpr (!BF16) m1l[row][col] = lo;
        }
    }
    __syncthreads();

    // ---- layer 2 ----
    f32x4_t acc2[4];
#pragma unroll
    for (int c = 0; c < 4; ++c) { acc2[c][0] = 0.f; acc2[c][1] = 0.f; acc2[c][2] = 0.f; acc2[c][3] = 0.f; }

    for (int k0 = 0; k0 < HH; k0 += 32) {
        short8_t amh = *reinterpret_cast<const short8_t*>(&m1h[rt * 16 + lr][k0 + 8 * hq]);
        short8_t aml;
        if constexpr (!BF16) aml = *reinterpret_cast<const short8_t*>(&m1l[rt * 16 + lr][k0 + 8 * hq]);
        const int ks = k0 >> 5;
#pragma unroll
        for (int c = 0; c < 4; ++c) {
            size_t po = ((size_t)(ks * 8 + ct0 + c)) * 512 + (size_t)lane * 8;
            short8_t bh = *reinterpret_cast<const short8_t*>(w2h + po);
            acc2[c] = mfma16(amh, bh, acc2[c]);
            if constexpr (!BF16) {
                short8_t bl = *reinterpret_cast<const short8_t*>(w2l + po);
                acc2[c] = mfma16(aml, bh, acc2[c]);
                acc2[c] = mfma16(amh, bl, acc2[c]);
            }
        }
    }
    {
        const int bb = row0 >> 11, nb = row0 & 2047;
#pragma unroll
        for (int c = 0; c < 4; ++c) {
            int col = (ct0 + c) * 16 + lr;
            float bv = b2f[col];
#pragma unroll
            for (int q = 0; q < 4; ++q) {
                int nn = nb + rt * 16 + hq * 4 + q;
                float v = fmaxf(acc2[c][q] + bv, 0.f);
                ushort_t hi, lo;
                split2(v, hi, lo);
                size_t po = (((size_t)(bb * 64 + (nn >> 5)) * 8 + (ct0 + c)) * 64
                             + lr + 16 * ((nn >> 3) & 3)) * 8 + (nn & 7);
                mTh[po] = hi;
                if constexpr (SPLIT) mTl[po] = lo;
            }
        }
    }
}

template<bool SPLIT>
__global__ __launch_bounds__(256) void mlp_kernel(
    const int* __restrict__ flag, const void* __restrict__ h, char* __restrict__ ws)
{
    __shared__ __align__(16) char smem[50688];
    if (*flag) mlp_body<true, false>(smem, h, ws);
    else       mlp_body<false, SPLIT>(smem, h, ws);
}

// ---------------------------------------------------------------------------
// msg = relu(A@m) via MFMA.  Deep-pipelined: 4-deep register ring for A,
// double-buffered LDS tiles, ONE raw barrier per k-tile (lgkmcnt drain only
// -- NO vmcnt(0), so A prefetch loads stay in flight across barriers).
// K-LOOP IS FULLY UNROLLED: every ring index is compile-time (rule #20 --
// R6's runtime `slot = t&3` put the ring in scratch: VGPR=36, 136MB of
// scratch writes, +18us.  Static indices keep it in registers).
// ---------------------------------------------------------------------------
template<bool BF16, bool SPLIT>
__device__ void msg_body(char* smem, const void* A, const char* ws, void* out)
{
    ushort_t (*Ah)[32][72] = (ushort_t(*)[32][72])smem;            // 2*4608 = 9216
    ushort_t (*Al)[32][72] = (ushort_t(*)[32][72])(smem + 9216);   // fp32 only
    const ushort_t* mThp = (const ushort_t*)(ws + WS_M);
    const ushort_t* mTlp = (const ushort_t*)(ws + WS_MLO);

    const int tid = threadIdx.x;
    const int b = blockIdx.x & 7, rtile = blockIdx.x >> 3;
    const int n0 = rtile * 32;
    const int lane = tid & 63, wv = tid >> 6;
    const int lr = lane & 15, hq = lane >> 4;
    const int wr = (wv & 1) * 16, wc4 = (wv >> 1) * 4;

    f32x4_t acc[4];
#pragma unroll
    for (int t = 0; t < 4; ++t) { acc[t][0] = 0.f; acc[t][1] = 0.f; acc[t][2] = 0.f; acc[t][3] = 0.f; }

    const int er0 = tid >> 4, ec0 = (tid & 15) * 4;   // fp32 staging map
    const int br_ = tid >> 3, bc_ = (tid & 7) * 8;    // bf16 staging map

    short8_t rB[4];
    float4   rF0[4], rF1[4];

    auto issue = [&](int t) {         // t compile-time after full unroll
        int slot = t & 3;
        if constexpr (BF16) {
            rB[slot] = *reinterpret_cast<const short8_t*>(
                (const ushort_t*)A + ((size_t)(b * NN + n0 + br_)) * NN + t * 64 + bc_);
        } else {
            const float* ap = (const float*)A;
            rF0[slot] = *reinterpret_cast<const float4*>(ap + ((size_t)(b * NN + n0 + er0)) * NN + t * 64 + ec0);
            rF1[slot] = *reinterpret_cast<const float4*>(ap + ((size_t)(b * NN + n0 + er0 + 16)) * NN + t * 64 + ec0);
        }
    };
    auto stage = [&](int t) {
        int slot = t & 3, buf = t & 1;
        if constexpr (BF16) {
            *reinterpret_cast<short8_t*>(&Ah[buf][br_][bc_]) = rB[slot];
        } else {
            ushort4 h4, l4;
            float4 v = rF0[slot];
            split2(v.x, h4.x, l4.x); split2(v.y, h4.y, l4.y);
            split2(v.z, h4.z, l4.z); split2(v.w, h4.w, l4.w);
            *reinterpret_cast<ushort4*>(&Ah[buf][er0][ec0]) = h4;
            *reinterpret_cast<ushort4*>(&Al[buf][er0][ec0]) = l4;
            v = rF1[slot];
            split2(v.x, h4.x, l4.x); split2(v.y, h4.y, l4.y);
            split2(v.z, h4.z, l4.z); split2(v.w, h4.w, l4.w);
            *reinterpret_cast<ushort4*>(&Ah[buf][er0 + 16][ec0]) = h4;
            *reinterpret_cast<ushort4*>(&Al[buf][er0 + 16][ec0]) = l4;
        }
    };

    // prologue: tiles 0..3 issued; tile0 staged into buf0
    issue(0); issue(1);
    stage(0);
    issue(2); issue(3);
    lds_barrier();

#pragma unroll                         // FULL unroll: kt compile-time
    for (int kt = 0; kt < 32; ++kt) {
        if (kt + 1 < 32) stage(kt + 1);       // buf[(kt+1)&1]; readers finished last iter
        const int cur = kt & 1;
#pragma unroll
        for (int kh = 0; kh < 2; ++kh) {
            short8_t ah = *reinterpret_cast<const short8_t*>(&Ah[cur][wr + lr][kh * 32 + 8 * hq]);
            short8_t al;
            if constexpr (!BF16) al = *reinterpret_cast<const short8_t*>(&Al[cur][wr + lr][kh * 32 + 8 * hq]);
            const size_t pb = ((size_t)(b * 64 + kt * 2 + kh) * 8 + wc4) * 512 + (size_t)lane * 8;
            short8_t bh[4], bl[4];
#pragma unroll
            for (int t = 0; t < 4; ++t)
                bh[t] = *reinterpret_cast<const short8_t*>(mThp + pb + t * 512);
            if constexpr (!BF16 && SPLIT) {
#pragma unroll
                for (int t = 0; t < 4; ++t)
                    bl[t] = *reinterpret_cast<const short8_t*>(mTlp + pb + t * 512);
            }
            if (kh == 0 && kt + 4 < 32) issue(kt + 4);   // after B-loads: stays in flight
#pragma unroll
            for (int t = 0; t < 4; ++t) {
                acc[t] = mfma16(ah, bh[t], acc[t]);
                if constexpr (!BF16) {
                    acc[t] = mfma16(al, bh[t], acc[t]);
                    if constexpr (SPLIT) acc[t] = mfma16(ah, bl[t], acc[t]);
                }
            }
        }
        lds_barrier();
    }

    // ---- epilogue: stage results in LDS, store contiguous 16B chunks ----
    ushort_t (*Sh)[136] = (ushort_t(*)[136])smem;            // 8704 B
    ushort_t (*Sl)[136] = (ushort_t(*)[136])(smem + 8704);   // 8704 B (fp32)
    const int wc = wc4 * 16;
#pragma unroll
    for (int t = 0; t < 4; ++t)
#pragma unroll
        for (int q = 0; q < 4; ++q) {
            int row = wr + hq * 4 + q, col = wc + t * 16 + lr;
            float v = fmaxf(acc[t][q], 0.f);
            if constexpr (BF16) {
                Sh[row][col] = bf_rn(v);
            } else {
                ushort_t hi, lo;
                split2(v, hi, lo);
                Sh[row][col] = hi;
                Sl[row][col] = lo;
            }
        }
    __syncthreads();

    char* ob = (char*)out;
    if constexpr (BF16) {
#pragma unroll
        for (int j = 0; j < 2; ++j) {
            int c = j * 256 + tid;
            int row = c >> 4, o16 = c & 15;
            short8_t v = *reinterpret_cast<const short8_t*>(&Sh[row][o16 * 8]);
            *reinterpret_cast<short8_t*>(ob + (size_t)(b * NN + n0 + row) * 256 + o16 * 16) = v;
        }
    } else {
#pragma unroll
        for (int j = 0; j < 4; ++j) {
            int c = j * 256 + tid;
            int row = c >> 5, rem = c & 31;
            int half = rem >> 4, o16 = rem & 15;
            const ushort_t* src = half ? &Sl[row][o16 * 8] : &Sh[row][o16 * 8];
            short8_t v = *reinterpret_cast<const short8_t*>(src);
            *reinterpret_cast<short8_t*>(ob + (size_t)(b * NN + n0 + row) * 512 + half * 256 + o16 * 16) = v;
        }
    }
}

template<bool SPLIT>
__global__ __launch_bounds__(256) void msg_kernel(
    const int* __restrict__ flag, const void* __restrict__ A,
    const char* __restrict__ ws, void* __restrict__ out)
{
    __shared__ __align__(16) char smem[18432];
    if (*flag) msg_body<true, false>(smem, A, (const char*)ws, out);
    else       msg_body<false, SPLIT>(smem, A, (const char*)ws, out);
}

// ---------------------------------------------------------------------------
// GRU via MFMA, weights from packed frag-linear.  (unchanged)
// ---------------------------------------------------------------------------
template<bool BF16>
__device__ void gru_body(char* smem, const void* h, const char* ws, void* out)
{
    ushort_t (*msgh)[264] = (ushort_t(*)[264])smem;               // 16896
    ushort_t (*msgl)[264] = (ushort_t(*)[264])(smem + 16896);
    float    (*hf)[132]   = (float(*)[132])(smem + 33792);

    const ushort_t* wihh = (const ushort_t*)(ws + WS_WIHH);
    const ushort_t* wihl = (const ushort_t*)(ws + WS_WIHL);
    const ushort_t* whhh = (const ushort_t*)(ws + WS_WHHH);
    const ushort_t* whhl = (const ushort_t*)(ws + WS_WHHL);
    const float* bihf = (const float*)(ws + WS_BIH);
    const float* bhhf = (const float*)(ws + WS_BHH);

    const int tid = threadIdx.x;
    const int row0 = blockIdx.x * 32;
    char* ob = (char*)out;

    if constexpr (BF16) {
#pragma unroll
        for (int j = 0; j < 2; ++j) {
            int e = j * 256 + tid;
            int r = e >> 4, c8 = (e & 15) * 8;
            short8_t v = *reinterpret_cast<const short8_t*>(ob + (size_t)(row0 + r) * 256 + c8 * 2);
            *(short8_t*)&msgh[r][c8] = v;
        }
    } else {
#pragma unroll
        for (int j = 0; j < 4; ++j) {
            int e = j * 256 + tid;
            int r = e >> 5, off = (e & 31) * 16;
            short8_t v = *reinterpret_cast<const short8_t*>(ob + (size_t)(row0 + r) * 512 + off);
            if (off < 256) *(short8_t*)&msgh[r][off >> 1] = v;
            else           *(short8_t*)&msgl[r][(off - 256) >> 1] = v;
        }
    }
    if constexpr (BF16) {
#pragma unroll
        for (int j = 0; j < 2; ++j) {
            int e = j * 256 + tid;
            int r = e >> 4, c8 = (e & 15) * 8;
            short8_t v = *reinterpret_cast<const short8_t*>((const ushort_t*)h + (size_t)(row0 + r) * HH + c8);
#pragma unroll
            for (int q = 0; q < 8; ++q) hf[r][c8 + q] = bfs_to_f(v[q]);
        }
    } else {
#pragma unroll
        for (int j = 0; j < 4; ++j) {
            int e = j * 256 + tid;
            int r = e >> 5, c4 = (e & 31) * 4;
            *(float4*)&hf[r][c4] = *reinterpret_cast<const float4*>((const float*)h + (size_t)(row0 + r) * HH + c4);
        }
    }
    __syncthreads();

    const int lane = tid & 63, wv = tid >> 6;
    const int lr = lane & 15, hq = lane >> 4;
    const int cw0 = wv * 32;

    f32x4_t accx[2][3][2], acch[2][3][2];
#pragma unroll
    for (int rt = 0; rt < 2; ++rt)
#pragma unroll
        for (int g = 0; g < 3; ++g)
#pragma unroll
            for (int ct = 0; ct < 2; ++ct) {
                accx[rt][g][ct][0] = 0.f; accx[rt][g][ct][1] = 0.f;
                accx[rt][g][ct][2] = 0.f; accx[rt][g][ct][3] = 0.f;
                acch[rt][g][ct][0] = 0.f; acch[rt][g][ct][1] = 0.f;
                acch[rt][g][ct][2] = 0.f; acch[rt][g][ct][3] = 0.f;
            }

    for (int k0 = 0; k0 < HH; k0 += 32) {
        short8_t amh[2], aml[2], ahh[2], ahl[2];
#pragma unroll
        for (int rt = 0; rt < 2; ++rt) {
            amh[rt] = *reinterpret_cast<const short8_t*>(&msgh[rt * 16 + lr][k0 + 8 * hq]);
            if constexpr (!BF16)
                aml[rt] = *reinterpret_cast<const short8_t*>(&msgl[rt * 16 + lr][k0 + 8 * hq]);
            float4 f0 = *(const float4*)&hf[rt * 16 + lr][k0 + 8 * hq];
            float4 f1 = *(const float4*)&hf[rt * 16 + lr][k0 + 8 * hq + 4];
#pragma unroll
            for (int j = 0; j < 4; ++j) {
                ushort_t hi, lo;
                split2(f4c(f0, j), hi, lo); ahh[rt][j] = (short)hi; ahl[rt][j] = (short)lo;
                split2(f4c(f1, j), hi, lo); ahh[rt][j + 4] = (short)hi; ahl[rt][j + 4] = (short)lo;
            }
        }
        const int ks = k0 >> 5;
#pragma unroll
        for (int g = 0; g < 3; ++g)
#pragma unroll
            for (int ct = 0; ct < 2; ++ct) {
                const size_t po = ((size_t)(ks * 24 + g * 8 + wv * 2 + ct)) * 512 + (size_t)lane * 8;
                short8_t bxh  = *reinterpret_cast<const short8_t*>(wihh + po);
                short8_t bhh2 = *reinterpret_cast<const short8_t*>(whhh + po);
                short8_t bxl, bhl2;
                if constexpr (!BF16) {
                    bxl  = *reinterpret_cast<const short8_t*>(wihl + po);
                    bhl2 = *reinterpret_cast<const short8_t*>(whhl + po);
                }
#pragma unroll
                for (int rt = 0; rt < 2; ++rt) {
                    accx[rt][g][ct] = mfma16(amh[rt], bxh, accx[rt][g][ct]);
                    acch[rt][g][ct] = mfma16(ahh[rt], bhh2, acch[rt][g][ct]);
                    if constexpr (!BF16) {
                        accx[rt][g][ct] = mfma16(aml[rt], bxh, accx[rt][g][ct]);
                        accx[rt][g][ct] = mfma16(amh[rt], bxl, accx[rt][g][ct]);
                        acch[rt][g][ct] = mfma16(ahl[rt], bhh2, acch[rt][g][ct]);
                        acch[rt][g][ct] = mfma16(ahh[rt], bhl2, acch[rt][g][ct]);
                    }
                }
            }
    }

#pragma unroll
    for (int rt = 0; rt < 2; ++rt)
#pragma unroll
        for (int ct = 0; ct < 2; ++ct) {
            int col = cw0 + ct * 16 + lr;
            float brx = bihf[col],       brh = bhhf[col];
            float bzx = bihf[128 + col], bzh = bhhf[128 + col];
            float bnx = bihf[256 + col], bnh = bhhf[256 + col];
#pragma unroll
            for (int q = 0; q < 4; ++q) {
                int row = rt * 16 + hq * 4 + q;
                float gr_ = (accx[rt][0][ct][q] + brx) + (acch[rt][0][ct][q] + brh);
                float gz_ = (accx[rt][1][ct][q] + bzx) + (acch[rt][1][ct][q] + bzh);
                float gxn = accx[rt][2][ct][q] + bnx;
                float ghn = acch[rt][2][ct][q] + bnh;
                float rr = 1.f / (1.f + expf(-gr_));
                float zz = 1.f / (1.f + expf(-gz_));
                float nv = tanhf(gxn + rr * ghn);
                float hv = hf[row][col];
                float res = (1.f - zz) * nv + zz * hv;
                size_t o = (size_t)(row0 + row) * HH + col;
                if constexpr (BF16) ((ushort_t*)out)[o] = bf_rn(res);
                else                ((float*)out)[o]    = res;
            }
        }
}

__global__ __launch_bounds__(256) __attribute__((amdgpu_waves_per_eu(1, 2)))
void gru_kernel(
    const int* __restrict__ flag, const void* __restrict__ h,
    const char* __restrict__ ws, void* __restrict__ out)
{
    __shared__ __align__(16) char smem[50688];
    if (*flag) gru_body<true >(smem, h, (const char*)ws, out);
    else       gru_body<false>(smem, h, (const char*)ws, out);
}

// ---------------------------------------------------------------------------
// diagnostic fill
// ---------------------------------------------------------------------------
__global__ void diag_kernel(float* __restrict__ out, float val, int nfill)
{
    int i = blockIdx.x * 256 + threadIdx.x;
    if (i < nfill) out[i] = val;
}

// ---------------------------------------------------------------------------
extern "C" void kernel_launch(void* const* d_in, const int* in_sizes, int n_in,
                              void* d_out, int out_size, void* d_ws, size_t ws_size,
                              hipStream_t stream)
{
    const int expected[10] = {BN * HH, BB * NN * NN, HH * HH, HH, HH * HH, HH,
                              3 * HH * HH, 3 * HH * HH, 3 * HH, 3 * HH};
    int bad = -1;
    if (n_in < 10) bad = 50;
    else {
        for (int i = 0; i < 10; ++i)
            if (in_sizes[i] != expected[i]) { bad = i; break; }
    }
    if (bad < 0 && out_size != BN * HH) bad = 60;
    if (bad >= 0) {
        float val = 10000.0f + 1000.0f * (float)bad;
        int nfill = out_size / 2;
        diag_kernel<<<(nfill + 255) / 256, 256, 0, stream>>>((float*)d_out, val, nfill);
        return;
    }

    const void* h   = d_in[0];
    const void* A   = d_in[1];
    const void* W1  = d_in[2];
    const void* b1  = d_in[3];
    const void* W2  = d_in[4];
    const void* b2  = d_in[5];
    const void* Wih = d_in[6];
    const void* Whh = d_in[7];
    const void* bih = d_in[8];
    const void* bhh = d_in[9];

    const size_t need_bf  = WS_M + (size_t)BN * HH * 2;    // packed mT hi only
    const size_t need_f32 = WS_M + (size_t)BN * HH * 4;    // + packed mT lo
    if (ws_size < need_bf) {
        float val = 2000.0f + (float)(ws_size >> 10);
        int nfill = out_size / 2;
        diag_kernel<<<(nfill + 255) / 256, 256, 0, stream>>>((float*)d_out, val, nfill);
        return;
    }
    const bool split = (ws_size >= need_f32);
    int*  flag = (int*)d_ws;
    char* ws   = (char*)d_ws;

    prep_kernel<<<64, 256, 0, stream>>>((const ushort_t*)A, W1, b1, W2, b2,
                                        Wih, Whh, bih, bhh, ws, flag);

    if (split) {
        mlp_kernel<true ><<<BN / 32, 256, 0, stream>>>(flag, h, ws);
        msg_kernel<true ><<<BB * (NN / 32), 256, 0, stream>>>(flag, A, ws, d_out);
    } else {
        mlp_kernel<false><<<BN / 32, 256, 0, stream>>>(flag, h, ws);
        msg_kernel<false><<<BB * (NN / 32), 256, 0, stream>>>(flag, A, ws, d_out);
    }
    gru_kernel<<<BN / 32, 256, 0, stream>>>(flag, h, ws, d_out);
}